// Round 11
// baseline (992.286 us; speedup 1.0000x reference)
//
#include <hip/hip_runtime.h>

// LinearModel: y[b,l], logits[b,c,l] from per-label 2-layer MLP.
// B=32 C=64 E=512 L=100. One GEMM M=2048 K=512 N=51200 (~107 GFLOP), bf16 MFMA.
// R10: 256x256 block (8 waves, wave 128x64), counted-vmcnt deep pipeline:
// per phase (ks-slice of 32): stage(t+1 slice) -> s_waitcnt vmcnt(8) -> raw
// s_barrier -> 12x ds_read_b128 -> 32x MFMA. Loads stay in flight across
// barriers (T3+T4); LDS ratio 43.7 FLOP/B -> compute-bound regime.
// Tile images are ks-sliced + bank-swizzled (s=(row>>1)&3 XOR on 16B blocks).

typedef unsigned short u16;
typedef unsigned int   u32;
typedef __attribute__((ext_vector_type(8))) short short8;
typedef __attribute__((ext_vector_type(4))) float f32x4;
typedef __attribute__((address_space(1))) const u32 as1_u32;
typedef __attribute__((address_space(3))) u32 as3_u32;

#define E_DIM 512
#define L_DIM 100
#define Y_SZ  3200            // 32*100
#define LG_OFF 3200

__device__ __forceinline__ u16 f2bf(float f) {
  union { float f; u32 u; } v; v.f = f;
  u32 u = v.u;
  u32 r = u + 0x7fffu + ((u >> 16) & 1u);   // round-to-nearest-even
  return (u16)(r >> 16);
}

// ---------------- pre-kernel 1: c_emb f32 -> A tile image -------------------
// A image: slice id = (mt*8 + kt)*2 + ks  (mt: 256-row tile, kt: K64, ks: K32)
// within slice (8192 u16): row*32 + ((bp ^ s(row))<<3) + j,  s=(row>>1)&3
__global__ __launch_bounds__(256) void conv_a_kernel(const float* __restrict__ src,
                                                     u16* __restrict__ dst) {
  int g = blockIdx.x * 256 + threadIdx.x;       // 131072 threads
  int base = g << 3;                             // 8 elems each (one block)
  int bc = base >> 9;
  int e  = base & 511;
  const float4* p = (const float4*)(src + base);
  float4 v0 = p[0];
  float4 v1 = p[1];
  union { u16 h[8]; uint4 q; } u;
  u.h[0]=f2bf(v0.x); u.h[1]=f2bf(v0.y); u.h[2]=f2bf(v0.z); u.h[3]=f2bf(v0.w);
  u.h[4]=f2bf(v1.x); u.h[5]=f2bf(v1.y); u.h[6]=f2bf(v1.z); u.h[7]=f2bf(v1.w);
  int mt = bc >> 8, row = bc & 255;
  int kt = e >> 6, ks = (e >> 5) & 1, bp = (e >> 3) & 3;
  int s = (row >> 1) & 3;
  int idx = ((mt*8 + kt)*2 + ks)*8192 + row*32 + ((bp ^ s) << 3);
  *(uint4*)(dst + idx) = u.q;
}

// ---------------- pre-kernel 2: W1[l][e][h] -> B tile image -----------------
// B image: slice id = ((l*2 + nb)*8 + kt)*2 + ks; within-slice same as A.
__global__ __launch_bounds__(256) void conv_w_kernel(const float* __restrict__ W1,
                                                     u16* __restrict__ dst) {
  __shared__ float T[64][65];                    // [e_local][h_local], +1 pad
  int blk = blockIdx.x;                          // 100*64 = 6400
  int l = blk >> 6;
  int rem = blk & 63;
  int et = rem >> 3, ht = rem & 7;               // 64x64 tile of (e,h)
  int tid = threadIdx.x;
  int e0 = et*64, h0 = ht*64;
  const float* basep = W1 + (size_t)l * (E_DIM*E_DIM);
  int erow = tid >> 4;                           // 0..15
  int hq = (tid & 15) * 4;                       // 0..60
  #pragma unroll
  for (int i = 0; i < 4; ++i) {
    int e = erow + i*16;
    float4 v = *(const float4*)(basep + (size_t)(e0 + e)*E_DIM + h0 + hq);
    T[e][hq+0] = v.x; T[e][hq+1] = v.y; T[e][hq+2] = v.z; T[e][hq+3] = v.w;
  }
  __syncthreads();
  int rl_h = tid >> 3;                           // 0..31
  int c0 = (tid & 7) * 8;                        // e_local chunk (one block)
  int ks = c0 >> 5, bp = (c0 >> 3) & 3;
  #pragma unroll
  for (int p = 0; p < 2; ++p) {
    int r_local = p*32 + rl_h;                   // h within 64-tile
    union { u16 h[8]; uint4 q; } u;
    #pragma unroll
    for (int j = 0; j < 8; ++j) u.h[j] = f2bf(T[c0 + j][r_local]);
    int hgl = h0 + r_local;
    int nb = hgl >> 8, row = hgl & 255;
    int s = (row >> 1) & 3;
    size_t idx = (size_t)((((l*2 + nb)*8 + et)*2 + ks))*8192
               + row*32 + ((bp ^ s) << 3);
    *(uint4*)(dst + idx) = u.q;
  }
}

// ---------------- main fused GEMM (256^2, counted-vmcnt pipeline) -----------
__global__ __launch_bounds__(512, 2) void gemm_kernel(
    const u16* __restrict__ Aws, const u16* __restrict__ Wws,
    const float* __restrict__ c_pred, const float* __restrict__ b1,
    const float* __restrict__ W2, const float* __restrict__ b2,
    float* __restrict__ out)
{
  __shared__ __align__(16) u16 As[2][2][8192];   // [parity][ks][256x32] 64 KB
  __shared__ __align__(16) u16 Bs[2][2][8192];   // 64 KB (total 128 KB)

  // 800 blocks = mt(8) x l(100); XCD-bijective swizzle (800 % 8 == 0).
  const int wg  = blockIdx.x;
  const int swzid = (wg & 7) * 100 + (wg >> 3);
  const int l   = swzid >> 3;                    // 0..99
  const int mt  = swzid & 7;                     // 0..7
  const int tid = threadIdx.x;
  const int wid = tid >> 6;                      // 0..7
  const int lane = tid & 63;
  const int wr = wid >> 2;                       // 0..1 -> 128 M rows
  const int wn = wid & 3;                        // 0..3 -> 64 N cols
  const int lr = lane & 15;
  const int lgp = lane >> 4;

  // preload epilogue coefficients (keeps mid-loop free of extra vmem)
  float b1v0[4], w2v0[4], b1v1[4], w2v1[4];
  #pragma unroll
  for (int ni = 0; ni < 4; ++ni) {
    int h = wn*64 + ni*16 + lr;
    b1v0[ni] = b1[l*E_DIM + h];        w2v0[ni] = W2[l*E_DIM + h];
    b1v1[ni] = b1[l*E_DIM + 256 + h];  w2v1[ni] = W2[l*E_DIM + 256 + h];
  }

  // LDS frag offsets (u16). s=(row>>1)&3 is invariant under row+=16.
  const int rA = wr*128 + lr;
  const int aU = rA*32 + ((lgp ^ ((rA >> 1) & 3)) << 3);
  const int rB = wn*64 + lr;
  const int bU = rB*32 + ((lgp ^ ((rB >> 1) & 3)) << 3);

  // stage one (A+B) ks-slice pair of virtual tile vt: 4 loads/wave, FIFO unit
  auto stage = [&](int vt, int ks) {
    const int kt = vt & 7, nb = vt >> 3, pp = vt & 1;
    const u16* asrc = Aws + (size_t)((mt*8 + kt)*2 + ks)*8192 + wid*1024 + lane*8;
    const u16* bsrc = Wws + (size_t)(((l*2 + nb)*8 + kt)*2 + ks)*8192 + wid*1024 + lane*8;
    u16* ad = &As[pp][ks][wid*1024];             // wave-uniform dest
    u16* bd = &Bs[pp][ks][wid*1024];
    __builtin_amdgcn_global_load_lds((as1_u32*)asrc,       (as3_u32*)ad,       16, 0, 0);
    __builtin_amdgcn_global_load_lds((as1_u32*)(asrc+512), (as3_u32*)(ad+512), 16, 0, 0);
    __builtin_amdgcn_global_load_lds((as1_u32*)bsrc,       (as3_u32*)bd,       16, 0, 0);
    __builtin_amdgcn_global_load_lds((as1_u32*)(bsrc+512), (as3_u32*)(bd+512), 16, 0, 0);
  };

  f32x4 acc[8][4];
  #pragma unroll
  for (int mi = 0; mi < 8; ++mi)
    #pragma unroll
    for (int ni = 0; ni < 4; ++ni) acc[mi][ni] = (f32x4){0.f,0.f,0.f,0.f};
  float wacc[8][4];
  #pragma unroll
  for (int mi = 0; mi < 8; ++mi)
    #pragma unroll
    for (int r = 0; r < 4; ++r) wacc[mi][r] = 0.f;

  auto compute = [&](int pp, int ks) {
    short8 af[8], bf[4];
    #pragma unroll
    for (int ni = 0; ni < 4; ++ni)
      bf[ni] = *(const short8*)&Bs[pp][ks][bU + ni*512];
    #pragma unroll
    for (int mi = 0; mi < 8; ++mi)
      af[mi] = *(const short8*)&As[pp][ks][aU + mi*512];
    #pragma unroll
    for (int mi = 0; mi < 8; ++mi)
      #pragma unroll
      for (int ni = 0; ni < 4; ++ni)
        acc[mi][ni] = __builtin_amdgcn_mfma_f32_16x16x32_bf16(
            af[mi], bf[ni], acc[mi][ni], 0, 0, 0);
  };

  auto fold = [&](const float* b1v, const float* w2v) {
    #pragma unroll
    for (int mi = 0; mi < 8; ++mi)
      #pragma unroll
      for (int ni = 0; ni < 4; ++ni)
        #pragma unroll
        for (int r = 0; r < 4; ++r) {
          float v = fmaxf(acc[mi][ni][r] + b1v[ni], 0.f);
          wacc[mi][r] = fmaf(v, w2v[ni], wacc[mi][r]);
          acc[mi][ni][r] = 0.f;
        }
  };

  // prologue: first tile's two slices in flight (8 loads/wave)
  stage(0, 0); stage(0, 1);

  // vt = nb*8 + kt; 16 virtual K-tiles of 64 (A re-staged for nb=1, L2-hot).
  for (int vt = 0; vt < 16; ++vt) {
    const int pp = vt & 1;
    // phase ks=0
    if (vt < 15) { stage(vt+1, 0); asm volatile("s_waitcnt vmcnt(8)" ::: "memory"); }
    else         {                 asm volatile("s_waitcnt vmcnt(4)" ::: "memory"); }
    __builtin_amdgcn_sched_barrier(0);
    __builtin_amdgcn_s_barrier();
    __builtin_amdgcn_sched_barrier(0);
    compute(pp, 0);
    // phase ks=1
    if (vt < 15) { stage(vt+1, 1); asm volatile("s_waitcnt vmcnt(8)" ::: "memory"); }
    else         {                 asm volatile("s_waitcnt vmcnt(0)" ::: "memory"); }
    __builtin_amdgcn_sched_barrier(0);
    __builtin_amdgcn_s_barrier();
    __builtin_amdgcn_sched_barrier(0);
    compute(pp, 1);
    if (vt == 7)       fold(b1v0, w2v0);   // end of nb=0 half
    else if (vt == 15) fold(b1v1, w2v1);   // end of nb=1 half
  }

  __syncthreads();                               // all compute done; reuse LDS

  // reduce wacc over the 16 col-lanes (cols live in lane&15)
  #pragma unroll
  for (int mi = 0; mi < 8; ++mi)
    #pragma unroll
    for (int r = 0; r < 4; ++r) {
      float s = wacc[mi][r];
      s += __shfl_xor(s, 1);
      s += __shfl_xor(s, 2);
      s += __shfl_xor(s, 4);
      s += __shfl_xor(s, 8);
      wacc[mi][r] = s;
    }

  float (*w_part)[256] = (float(*)[256])&As[0][0][0];  // 4 KB scratch
  if (lr == 0) {
    #pragma unroll
    for (int mi = 0; mi < 8; ++mi)
      #pragma unroll
      for (int r = 0; r < 4; ++r)
        w_part[wn][wr*128 + mi*16 + lgp*4 + r] = wacc[mi][r];
  }
  __syncthreads();

  if (tid < 256) {
    int row = tid;
    float w = w_part[0][row] + w_part[1][row] + w_part[2][row] + w_part[3][row]
            + b2[l];
    int bcg = mt*256 + row;
    float lgt = w * c_pred[bcg];
    out[LG_OFF + bcg*L_DIM + l] = lgt;
    float s = lgt;
    s += __shfl_down(s, 32);
    s += __shfl_down(s, 16);
    s += __shfl_down(s, 8);
    s += __shfl_down(s, 4);
    s += __shfl_down(s, 2);
    s += __shfl_down(s, 1);
    if (lane == 0) out[(bcg >> 6)*L_DIM + l] = s;   // y[b,l]
  }
}

// ---------------- fallback (ws too small): correct fp32 path ---------------
__global__ __launch_bounds__(256) void naive_kernel(
    const float* __restrict__ c_emb, const float* __restrict__ c_pred,
    const float* __restrict__ W1, const float* __restrict__ b1,
    const float* __restrict__ W2, const float* __restrict__ b2,
    float* __restrict__ out)
{
  __shared__ float a_lds[16][512];
  __shared__ float wsum[4][16];
  int l = blockIdx.y;
  int rt = blockIdx.x;                           // 128 tiles of 16 rows
  int tid = threadIdx.x, lane = tid & 63, wid = tid >> 6;
  int row0 = rt * 16;
  #pragma unroll
  for (int i = 0; i < 8; ++i) {
    int flat = i*1024 + tid*4;
    int r = flat >> 9, e = flat & 511;
    *(float4*)&a_lds[r][e] = *(const float4*)&c_emb[(size_t)(row0 + r)*E_DIM + e];
  }
  __syncthreads();
  int h0 = tid, h1 = tid + 256;
  const float* w1b = W1 + (size_t)l * (E_DIM*E_DIM);
  float acc0[16], acc1[16];
  #pragma unroll
  for (int r = 0; r < 16; ++r) { acc0[r] = 0.f; acc1[r] = 0.f; }
  for (int e = 0; e < E_DIM; ++e) {
    float wa = w1b[(size_t)e*E_DIM + h0];
    float wb = w1b[(size_t)e*E_DIM + h1];
    #pragma unroll
    for (int r = 0; r < 16; ++r) {
      float a = a_lds[r][e];
      acc0[r] = fmaf(a, wa, acc0[r]);
      acc1[r] = fmaf(a, wb, acc1[r]);
    }
  }
  float b1a = b1[l*E_DIM + h0], b1c = b1[l*E_DIM + h1];
  float w2a = W2[l*E_DIM + h0], w2c = W2[l*E_DIM + h1];
  float part[16];
  #pragma unroll
  for (int r = 0; r < 16; ++r) {
    float v0 = fmaxf(acc0[r] + b1a, 0.f) * w2a;
    float v1 = fmaxf(acc1[r] + b1c, 0.f) * w2c;
    part[r] = v0 + v1;
  }
  #pragma unroll
  for (int r = 0; r < 16; ++r) {
    float s = part[r];
    s += __shfl_down(s, 32); s += __shfl_down(s, 16); s += __shfl_down(s, 8);
    s += __shfl_down(s, 4);  s += __shfl_down(s, 2);  s += __shfl_down(s, 1);
    if (lane == 0) wsum[wid][r] = s;
  }
  __syncthreads();
  if (tid < 16) {
    float w = wsum[0][tid] + wsum[1][tid] + wsum[2][tid] + wsum[3][tid] + b2[l];
    int bc = row0 + tid;
    float lgt = w * c_pred[bc];
    out[LG_OFF + bc*L_DIM + l] = lgt;
    atomicAdd(&out[(bc >> 6)*L_DIM + l], lgt);
  }
}

extern "C" void kernel_launch(void* const* d_in, const int* in_sizes, int n_in,
                              void* d_out, int out_size, void* d_ws, size_t ws_size,
                              hipStream_t stream) {
  const float* c_emb  = (const float*)d_in[0];
  const float* c_pred = (const float*)d_in[1];
  const float* W1     = (const float*)d_in[2];
  const float* b1     = (const float*)d_in[3];
  const float* W2     = (const float*)d_in[4];
  const float* b2     = (const float*)d_in[5];
  float* out = (float*)d_out;

  const size_t nA = 1048576;       // 32*64*512
  const size_t nW = 26214400;      // 100*512*512
  const size_t need = 2*nA + 2*nW; // bf16 copies: ~54.5 MB

  if (ws_size >= need) {
    u16* Aws = (u16*)d_ws;
    u16* Wws = (u16*)d_ws + nA;
    conv_a_kernel<<<512, 256, 0, stream>>>(c_emb, Aws);
    conv_w_kernel<<<6400, 256, 0, stream>>>(W1, Wws);
    gemm_kernel<<<800, 512, 0, stream>>>(Aws, Wws, c_pred, b1, W2, b2, out);
  } else {
    hipMemsetAsync(out, 0, Y_SZ*sizeof(float), stream);  // y accumulated via atomics
    naive_kernel<<<dim3(128, 100), 256, 0, stream>>>(c_emb, c_pred, W1, b1, W2, b2, out);
  }
}